// Round 9
// baseline (480.027 us; speedup 1.0000x reference)
//
#include <hip/hip_runtime.h>

#define N_NODES   50000
#define N_EDGES   1600000
#define FDIM_IN   128
#define HDIM      160
#define N_GRAPHS  512
#define BN_EPS    1e-5f
#define NBKT_MAX  256           // coarse buckets of 256 nodes (N<=65536)
#define BKT_SH    8             // log2(nodes per bucket)
#define HIST_BLOCKS 128         // cg stays 128KB (R5/R8 workspace footprint)

typedef _Float16 h2   __attribute__((ext_vector_type(2)));   // packed f16 pair
typedef _Float16 f16x8 __attribute__((ext_vector_type(8)));  // MFMA f16 fragment (4 VGPR)
typedef float  facc4 __attribute__((ext_vector_type(4)));    // 4 x f32

// ---------------- f16 helpers ----------------

__device__ __forceinline__ unsigned short f2h_bits(float f) {
    union { _Float16 h; unsigned short s; } c;
    c.h = (_Float16)f;
    return c.s;
}

__device__ __forceinline__ unsigned int pkh(float lo, float hi) {
    return (unsigned int)f2h_bits(lo) | ((unsigned int)f2h_bits(hi) << 16);
}

__device__ __forceinline__ h2 u2h(unsigned int u) {
    union { unsigned int u; h2 h; } c; c.u = u; return c.h;
}

__device__ __forceinline__ unsigned int h2u(h2 h) {
    union { unsigned int u; h2 h; } c; c.h = h; return c.u;
}

// packed accumulate: 4 v_pk_add_f16 per 16B (vs 16 VALU for bf16 unpack path)
__device__ __forceinline__ void addpk16(h2* acc, uint4 r) {
    acc[0] += u2h(r.x);
    acc[1] += u2h(r.y);
    acc[2] += u2h(r.z);
    acc[3] += u2h(r.w);
}

// ---------------- two-level counting sort by dst ----------------

__global__ __launch_bounds__(256) void coarse_hist_kernel(const int* __restrict__ dst,
                                                          int* __restrict__ cg, int E) {
    __shared__ int h[NBKT_MAX];
    int tid = threadIdx.x;
    if (tid < NBKT_MAX) h[tid] = 0;
    __syncthreads();
    for (int e = blockIdx.x * 256 + tid; e < E; e += gridDim.x * 256)
        atomicAdd(&h[dst[e] >> BKT_SH], 1);
    __syncthreads();
    if (tid < NBKT_MAX) cg[blockIdx.x * NBKT_MAX + tid] = h[tid];
}

// ---------------- merged setup: scan (block 0) + BN fold (blocks 1-3) + weight pack ----------------

struct PrepArgs {
    const float *b, *g, *be, *m, *v;
    float *sc, *sh;
};

__global__ __launch_bounds__(256) void setup_kernel(const int* __restrict__ cg,
                                                    int* __restrict__ bucket_base,
                                                    int* __restrict__ bucket_cursor,
                                                    PrepArgs a0, PrepArgs a1, PrepArgs a2,
                                                    const float* __restrict__ W1,
                                                    const float* __restrict__ W2,
                                                    const float* __restrict__ W3,
                                                    unsigned short* __restrict__ o1,
                                                    unsigned short* __restrict__ o2,
                                                    unsigned short* __restrict__ o3) {
    int bid = blockIdx.x;
    int t = threadIdx.x;
    if (bid == 0) {
        __shared__ int h[NBKT_MAX];
        __shared__ int total;
        if (t < NBKT_MAX) {
            int s = 0;
            for (int b = 0; b < HIST_BLOCKS; ++b) s += cg[b * NBKT_MAX + t];
            h[t] = s;
        }
        __syncthreads();
        if (t == 0) {
            int run = 0;
            for (int i = 0; i < NBKT_MAX; ++i) { int c = h[i]; h[i] = run; run += c; }
            total = run;
        }
        __syncthreads();
        if (t < NBKT_MAX) {
            bucket_base[t] = h[t];
            bucket_cursor[t] = h[t];
        }
        if (t == 0) bucket_base[NBKT_MAX] = total;
    } else if (bid <= 3) {
        PrepArgs a = (bid == 1) ? a0 : (bid == 2) ? a1 : a2;
        if (t < HDIM) {
            float s = a.g[t] * rsqrtf(a.v[t] + BN_EPS);
            a.sc[t] = s;
            a.sh[t] = (a.b[t] - a.m[t]) * s + a.be[t];
        }
    } else {
        int i = (bid - 4) * 256 + t;     // packed index over all three weights
        const float* W;
        unsigned short* o;
        if (i < 128 * 160)                 { W = W1; o = o1; }
        else if (i < 128 * 160 + 160 * 160) { W = W2; o = o2; i -= 128 * 160; }
        else if (i < 128 * 160 + 2 * 160 * 160) { W = W3; o = o3; i -= 128 * 160 + 160 * 160; }
        else return;
        int j = i & 7;
        int l = (i >> 3) & 63;
        int u = (i >> 9) % 10;
        int tt = i / 5120;
        int k = tt * 32 + (l >> 4) * 8 + j;
        int nn = u * 16 + (l & 15);
        o[i] = f2h_bits(W[k * 160 + nn]);
    }
}

// level 1: partition packed (src<<8 | dst&255) into coarse-bucket-contiguous regions
__global__ __launch_bounds__(256) void part_kernel(const int* __restrict__ src,
                                                   const int* __restrict__ dst,
                                                   int* __restrict__ bucket_cursor,
                                                   unsigned int* __restrict__ pairs, int E) {
    __shared__ int bcnt[NBKT_MAX], bbase[NBKT_MAX], lc[NBKT_MAX];
    int tid = threadIdx.x;
    int per = (E + gridDim.x - 1) / gridDim.x;
    int beg = blockIdx.x * per;
    int end = min(beg + per, E);
    if (tid < NBKT_MAX) { bcnt[tid] = 0; lc[tid] = 0; }
    __syncthreads();
    for (int e = beg + tid; e < end; e += 256)
        atomicAdd(&bcnt[dst[e] >> BKT_SH], 1);
    __syncthreads();
    if (tid < NBKT_MAX)
        bbase[tid] = bcnt[tid] ? atomicAdd(&bucket_cursor[tid], bcnt[tid]) : 0;
    __syncthreads();
    for (int e = beg + tid; e < end; e += 256) {
        int d = dst[e];
        int b = d >> BKT_SH;
        int pos = bbase[b] + atomicAdd(&lc[b], 1);
        pairs[pos] = ((unsigned int)src[e] << BKT_SH) | (unsigned int)(d & (NBKT_MAX - 1));
    }
}

// level 2: per-bucket exact CSR build + local scatter + fused x*inv f16 pre-scale
__global__ __launch_bounds__(1024) void bucket_csr_kernel(const unsigned int* __restrict__ pairs,
                                                          const int* __restrict__ bucket_base,
                                                          int* __restrict__ row_off,
                                                          float* __restrict__ inv,
                                                          int* __restrict__ ssrc,
                                                          const float* __restrict__ x,
                                                          unsigned short* __restrict__ xs,
                                                          int n) {
    __shared__ int h[NBKT_MAX];
    __shared__ int ws[4];
    __shared__ float sinv[NBKT_MAX];
    int tid = threadIdx.x;
    int b = blockIdx.x;
    int node0 = b << BKT_SH;
    int beg = bucket_base[b], end = bucket_base[b + 1];
    if (tid < NBKT_MAX) h[tid] = 0;
    __syncthreads();
    for (int j = beg + tid; j < end; j += 1024)
        atomicAdd(&h[pairs[j] & (NBKT_MAX - 1)], 1);
    __syncthreads();
    int cntv = (tid < NBKT_MAX) ? h[tid] : 0;
    __syncthreads();
    int lane = tid & 63, wid = tid >> 6;
    int incl = cntv;
    #pragma unroll
    for (int off = 1; off < 64; off <<= 1) {
        int u = __shfl_up(incl, off);
        if (lane >= off) incl += u;
    }
    if (tid < NBKT_MAX && lane == 63) ws[wid] = incl;
    __syncthreads();
    if (tid == 0) {
        int r = 0;
        #pragma unroll
        for (int i = 0; i < 4; ++i) { int t = ws[i]; ws[i] = r; r += t; }
    }
    __syncthreads();
    int excl = (tid < NBKT_MAX) ? (ws[wid] + incl - cntv) : 0;
    if (tid < NBKT_MAX) {
        float iv = rsqrtf((float)(cntv + 1));    // +1 = self loop
        int node = node0 + tid;
        if (node < n) {
            row_off[node] = beg + excl;
            inv[node] = iv;
        }
        sinv[tid] = iv;
        h[tid] = excl;
    }
    if (tid == 0 && (node0 + NBKT_MAX) >= n) row_off[n] = end;
    __syncthreads();
    for (int j = beg + tid; j < end; j += 1024) {
        unsigned int p = pairs[j];
        int pos = beg + atomicAdd(&h[p & (NBKT_MAX - 1)], 1);
        ssrc[pos] = (int)(p >> BKT_SH);
    }
    // fused pre-scale: xs[node] = f16(x[node] * inv[node]) for this bucket's nodes
    for (int idx = tid; idx < NBKT_MAX * 32; idx += 1024) {
        int nd = node0 + (idx >> 5);
        if (nd < n) {
            float w = sinv[idx >> 5];
            float4 v = ((const float4*)x)[(size_t)nd * 32 + (idx & 31)];
            ushort4 o;
            o.x = f2h_bits(v.x * w); o.y = f2h_bits(v.y * w);
            o.z = f2h_bits(v.z * w); o.w = f2h_bits(v.w * w);
            ((ushort4*)xs)[(size_t)nd * 32 + (idx & 31)] = o;
        }
    }
}

// ---------------- grouped-gather aggregation (f16 in, f16 out) ----------------
// Wave per node; wave split into G groups of LPR lanes; each group gathers a
// different edge's row with uint4 (16B) loads. C=160: G=3x20; C=128: G=4x16.
// In-loop accumulate is packed f16 (v_pk_add_f16): 4 VALU per 16B vs 16 for bf16.
// Launched in TWO half-range dispatches (base param) so interior kernels >35us
// become visible in the profile top-5.

template <int C>
__global__ __launch_bounds__(256) void agg_grp_kernel(const unsigned short* __restrict__ in_s,
                                                      const float* __restrict__ inv,
                                                      const int* __restrict__ row_off,
                                                      const int* __restrict__ ssrc,
                                                      unsigned short* __restrict__ out,
                                                      int base, int n) {
    constexpr int LPR = C / 8;          // lanes per row (uint4 = 8 ch)
    constexpr int G   = 64 / LPR;       // concurrent edges per wave
    constexpr int RB  = C * 2;          // row bytes
    int wave = threadIdx.x >> 6;
    int lane = threadIdx.x & 63;
    int node = base + blockIdx.x * 4 + wave;
    if (node >= n) return;
    int g  = lane / LPR;
    int cl = lane - g * LPR;
    bool act = g < G;
    int beg = row_off[node], end = row_off[node + 1];
    const char* bptr = (const char*)in_s;
    int lb = cl * 16;

    h2 acc[4];
    #pragma unroll
    for (int i = 0; i < 4; ++i) acc[i] = (h2){(_Float16)0.f, (_Float16)0.f};

    if (g == 0) {   // self-loop term
        uint4 r = *(const uint4*)(bptr + (size_t)node * RB + lb);
        addpk16(acc, r);
    }

    int e = act ? beg + g : end;
    for (; e + G < end; e += 2 * G) {
        int s0 = ssrc[e], s1 = ssrc[e + G];
        uint4 r0 = *(const uint4*)(bptr + (size_t)s0 * RB + lb);
        uint4 r1 = *(const uint4*)(bptr + (size_t)s1 * RB + lb);
        addpk16(acc, r0);
        addpk16(acc, r1);
    }
    if (e < end) {
        uint4 r = *(const uint4*)(bptr + (size_t)ssrc[e] * RB + lb);
        addpk16(acc, r);
    }

    // cross-group combine (stays packed f16)
    if (G == 4) {
        #pragma unroll
        for (int i = 0; i < 4; ++i) acc[i] += u2h(__shfl(h2u(acc[i]), lane + 32));
        #pragma unroll
        for (int i = 0; i < 4; ++i) acc[i] += u2h(__shfl(h2u(acc[i]), lane + 16));
    } else {
        #pragma unroll
        for (int i = 0; i < 4; ++i) {
            unsigned int ua = __shfl(h2u(acc[i]), lane + 20);
            unsigned int ub = __shfl(h2u(acc[i]), lane + 40);
            acc[i] += u2h(ua) + u2h(ub);
        }
    }

    if (lane < LPR) {
        float wi = inv[node];      // final scale in fp32 for precision
        uint4 o;
        o.x = pkh((float)acc[0].x * wi, (float)acc[0].y * wi);
        o.y = pkh((float)acc[1].x * wi, (float)acc[1].y * wi);
        o.z = pkh((float)acc[2].x * wi, (float)acc[2].y * wi);
        o.w = pkh((float)acc[3].x * wi, (float)acc[3].y * wi);
        *(uint4*)((char*)out + (size_t)node * RB + lb) = o;
    }
}

// ---------------- MFMA GEMM v2 (f16): B panel staged in LDS, 128 rows/block ----------------

template <int K, int OUTMODE>
__global__ __launch_bounds__(256) void mfma_gemm_kernel(const unsigned short* __restrict__ A,
                                                        const unsigned short* __restrict__ Bp,
                                                        const float* __restrict__ sc,
                                                        const float* __restrict__ sh,
                                                        const float* __restrict__ inv,
                                                        float* __restrict__ CoutF,
                                                        unsigned short* __restrict__ CoutB,
                                                        int n) {
    constexpr int KT = K / 32;
    constexpr int BQ = K * 20;                   // uint4 count of packed B panel
    __shared__ uint4 Bs[BQ];
    int tid = threadIdx.x;
    for (int i = tid; i < BQ; i += 256) Bs[i] = ((const uint4*)Bp)[i];

    int wave = tid >> 6, lane = tid & 63;
    int m = lane & 15, q = lane >> 4;
    int row0 = blockIdx.x * 128 + wave * 16;     // row-group 0
    int row1 = row0 + 64;                        // row-group 1

    int ar0 = row0 + m; ar0 = (ar0 < n) ? ar0 : (n - 1);
    int ar1 = row1 + m; ar1 = (ar1 < n) ? ar1 : (n - 1);
    const f16x8* A0 = (const f16x8*)(A + (size_t)ar0 * K);   // frag idx = t*4 + q
    const f16x8* A1 = (const f16x8*)(A + (size_t)ar1 * K);
    const f16x8* Bf = (const f16x8*)Bs;                      // frag idx = (t*10+u)*64 + lane

    facc4 acc0[10], acc1[10];
    #pragma unroll
    for (int u = 0; u < 10; ++u) {
        acc0[u] = (facc4){0.f, 0.f, 0.f, 0.f};
        acc1[u] = (facc4){0.f, 0.f, 0.f, 0.f};
    }

    __syncthreads();

    #pragma unroll
    for (int t = 0; t < KT; ++t) {
        f16x8 af0 = A0[t * 4 + q];
        f16x8 af1 = A1[t * 4 + q];
        #pragma unroll
        for (int u = 0; u < 10; ++u) {
            f16x8 bf = Bf[(t * 10 + u) * 64 + lane];
            acc0[u] = __builtin_amdgcn_mfma_f32_16x16x32_f16(af0, bf, acc0[u], 0, 0, 0);
            acc1[u] = __builtin_amdgcn_mfma_f32_16x16x32_f16(af1, bf, acc1[u], 0, 0, 0);
        }
    }

    // D layout: col = lane&15 (within tile), row = q*4 + reg
    #pragma unroll
    for (int u = 0; u < 10; ++u) {
        int c = u * 16 + m;
        float scv = sc[c], shv = sh[c];
        #pragma unroll
        for (int r = 0; r < 4; ++r) {
            int rr = row0 + q * 4 + r;
            if (rr < n) {
                float v = fmaxf(acc0[u][r] * scv + shv, 0.f);
                if (OUTMODE == 1) CoutB[(size_t)rr * 160 + c] = f2h_bits(v * inv[rr]);
                else              CoutF[(size_t)rr * 160 + c] = v;
            }
            int rr1 = row1 + q * 4 + r;
            if (rr1 < n) {
                float v = fmaxf(acc1[u][r] * scv + shv, 0.f);
                if (OUTMODE == 1) CoutB[(size_t)rr1 * 160 + c] = f2h_bits(v * inv[rr1]);
                else              CoutF[(size_t)rr1 * 160 + c] = v;
            }
        }
    }
}

// ---------------- mean pool (sorted batch) + MLP head ----------------

__global__ __launch_bounds__(256) void pool_head_kernel(const float* __restrict__ h,
                                                        const int* __restrict__ batch,
                                                        const float* __restrict__ Wc1,
                                                        const float* __restrict__ bc1,
                                                        const float* __restrict__ Wc2,
                                                        const float* __restrict__ bc2,
                                                        float* __restrict__ out, int n) {
    __shared__ float4 part[6][40];
    __shared__ float pooled[160];
    __shared__ float z[80];
    __shared__ int range[2];
    int g = blockIdx.x;
    int t = threadIdx.x;
    if (t < 2) {
        int target = g + t;
        int lo = 0, hi = n;
        while (lo < hi) {
            int mid = (lo + hi) >> 1;
            if (batch[mid] < target) lo = mid + 1; else hi = mid;
        }
        range[t] = lo;
    }
    __syncthreads();
    int lo = range[0], hi = range[1];
    int sub = t / 40, c4 = t - sub * 40;
    if (sub < 6) {
        float4 a = {0.f, 0.f, 0.f, 0.f};
        for (int r = lo + sub; r < hi; r += 6) {
            float4 v = ((const float4*)(h + (size_t)r * 160))[c4];
            a.x += v.x; a.y += v.y; a.z += v.z; a.w += v.w;
        }
        part[sub][c4] = a;
    }
    __syncthreads();
    if (t < 40) {
        float4 s = {0.f, 0.f, 0.f, 0.f};
        #pragma unroll
        for (int i = 0; i < 6; ++i) {
            float4 p = part[i][t];
            s.x += p.x; s.y += p.y; s.z += p.z; s.w += p.w;
        }
        float ic = 1.f / fmaxf((float)(hi - lo), 1.f);
        pooled[t * 4 + 0] = s.x * ic;
        pooled[t * 4 + 1] = s.y * ic;
        pooled[t * 4 + 2] = s.z * ic;
        pooled[t * 4 + 3] = s.w * ic;
    }
    __syncthreads();
    if (t < 80) {
        float s = bc1[t];
        for (int k = 0; k < 160; ++k) s += pooled[k] * Wc1[k * 80 + t];
        z[t] = fmaxf(s, 0.f);
    }
    __syncthreads();
    if (t < 2) {
        float s = bc2[t];
        for (int k = 0; k < 80; ++k) s += z[k] * Wc2[k * 2 + t];
        out[g * 2 + t] = s;
    }
}

// ---------------- launch ----------------

static inline size_t align256(size_t x) { return (x + 255) & ~(size_t)255; }

extern "C" void kernel_launch(void* const* d_in, const int* in_sizes, int n_in,
                              void* d_out, int out_size, void* d_ws, size_t ws_size,
                              hipStream_t stream) {
    const float* x   = (const float*)d_in[0];
    const int* ei    = (const int*)d_in[1];
    const int* batch = (const int*)d_in[2];
    const float* W1  = (const float*)d_in[3];
    const float* b1  = (const float*)d_in[4];
    const float* W2  = (const float*)d_in[5];
    const float* b2  = (const float*)d_in[6];
    const float* W3  = (const float*)d_in[7];
    const float* b3  = (const float*)d_in[8];
    const float* g1  = (const float*)d_in[9];
    const float* be1 = (const float*)d_in[10];
    const float* m1  = (const float*)d_in[11];
    const float* v1  = (const float*)d_in[12];
    const float* g2  = (const float*)d_in[13];
    const float* be2 = (const float*)d_in[14];
    const float* m2  = (const float*)d_in[15];
    const float* v2  = (const float*)d_in[16];
    const float* g3  = (const float*)d_in[17];
    const float* be3 = (const float*)d_in[18];
    const float* m3  = (const float*)d_in[19];
    const float* v3  = (const float*)d_in[20];
    const float* Wc1 = (const float*)d_in[21];
    const float* bc1 = (const float*)d_in[22];
    const float* Wc2 = (const float*)d_in[23];
    const float* bc2 = (const float*)d_in[24];
    float* out = (float*)d_out;

    const int N = in_sizes[2];          // 50000
    const int E = in_sizes[1] / 2;      // 1600000
    const int* src = ei;
    const int* dst = ei + E;

    char* w = (char*)d_ws;
    int*   row_off = (int*)w;             w += align256((size_t)(N + 1) * 4);
    float* inv     = (float*)w;           w += align256((size_t)N * 4);
    int*   ssrc    = (int*)w;             w += align256((size_t)E * 4);
    unsigned int* pairs = (unsigned int*)w; w += align256((size_t)E * 4);
    int*   cg      = (int*)w;             w += align256((size_t)HIST_BLOCKS * NBKT_MAX * 4);
    int*   bucket_base   = (int*)w;       w += align256((size_t)(NBKT_MAX + 1) * 4);
    int*   bucket_cursor = (int*)w;       w += align256((size_t)NBKT_MAX * 4);
    float* scsh    = (float*)w;           w += align256((size_t)6 * HDIM * 4);
    unsigned short* W1p = (unsigned short*)w;  w += align256((size_t)FDIM_IN * HDIM * 2);
    unsigned short* W2p = (unsigned short*)w;  w += align256((size_t)HDIM * HDIM * 2);
    unsigned short* W3p = (unsigned short*)w;  w += align256((size_t)HDIM * HDIM * 2);
    unsigned short* bufA_bf = (unsigned short*)w;  w += align256((size_t)N * HDIM * 2);
    char* regionR = w;                    // reused region
    unsigned short* xs_bf = (unsigned short*)regionR;                           // N*128*2
    unsigned short* hs_bf = (unsigned short*)(regionR + align256((size_t)N * FDIM_IN * 2)); // N*160*2
    float* bufB = (float*)regionR;        // final h3 fp32 (aliases xs/hs, both dead by then)
    float* sc1 = scsh, *sh1 = scsh + 160, *sc2 = scsh + 320, *sh2 = scsh + 480,
         * sc3 = scsh + 640, *sh3 = scsh + 800;

    // two-level counting sort by dst -> row_off, ssrc, inv (+ fused x pre-scale)
    coarse_hist_kernel<<<HIST_BLOCKS, 256, 0, stream>>>(dst, cg, E);

    PrepArgs pa0 = {b1, g1, be1, m1, v1, sc1, sh1};
    PrepArgs pa1 = {b2, g2, be2, m2, v2, sc2, sh2};
    PrepArgs pa2 = {b3, g3, be3, m3, v3, sc3, sh3};
    int packTotal = 128 * 160 + 2 * 160 * 160;
    int setupBlocks = 4 + (packTotal + 255) / 256;
    setup_kernel<<<setupBlocks, 256, 0, stream>>>(cg, bucket_base, bucket_cursor,
                                                  pa0, pa1, pa2, W1, W2, W3, W1p, W2p, W3p);

    part_kernel<<<256, 256, 0, stream>>>(src, dst, bucket_cursor, pairs, E);
    int nbkt = (N + NBKT_MAX - 1) >> BKT_SH;
    bucket_csr_kernel<<<nbkt, 1024, 0, stream>>>(pairs, bucket_base, row_off, inv, ssrc, x, xs_bf, N);

    // agg split into two half-range dispatches (visibility: interior kernels >35us
    // will now outrank agg halves in the profile top-5)
    int half = ((N / 2) + 3) & ~3;
    int gA1 = half / 4;
    int gA2 = (N - half + 3) / 4;
    int gGemm = (N + 127) / 128;

    // layer 1
    agg_grp_kernel<128><<<gA1, 256, 0, stream>>>(xs_bf, inv, row_off, ssrc, bufA_bf, 0, half);
    agg_grp_kernel<128><<<gA2, 256, 0, stream>>>(xs_bf, inv, row_off, ssrc, bufA_bf, half, N);
    mfma_gemm_kernel<128, 1><<<gGemm, 256, 0, stream>>>(bufA_bf, W1p, sc1, sh1, inv, nullptr, hs_bf, N);
    // layer 2
    agg_grp_kernel<160><<<gA1, 256, 0, stream>>>(hs_bf, inv, row_off, ssrc, bufA_bf, 0, half);
    agg_grp_kernel<160><<<gA2, 256, 0, stream>>>(hs_bf, inv, row_off, ssrc, bufA_bf, half, N);
    mfma_gemm_kernel<160, 1><<<gGemm, 256, 0, stream>>>(bufA_bf, W2p, sc2, sh2, inv, nullptr, hs_bf, N);
    // layer 3: fp32 unscaled h3 for pooling (bufB aliases dead xs/hs region)
    agg_grp_kernel<160><<<gA1, 256, 0, stream>>>(hs_bf, inv, row_off, ssrc, bufA_bf, 0, half);
    agg_grp_kernel<160><<<gA2, 256, 0, stream>>>(hs_bf, inv, row_off, ssrc, bufA_bf, half, N);
    mfma_gemm_kernel<160, 0><<<gGemm, 256, 0, stream>>>(bufA_bf, W3p, sc3, sh3, inv, bufB, nullptr, N);

    pool_head_kernel<<<N_GRAPHS, 256, 0, stream>>>(bufB, batch, Wc1, bc1, Wc2, bc2, out, N);
}

// Round 10
// 427.502 us; speedup vs baseline: 1.1229x; 1.1229x over previous
//
#include <hip/hip_runtime.h>

#define N_NODES   50000
#define N_EDGES   1600000
#define FDIM_IN   128
#define HDIM      160
#define N_GRAPHS  512
#define BN_EPS    1e-5f
#define NBKT_MAX  256           // coarse buckets of 256 nodes (N<=65536)
#define BKT_SH    8             // log2(nodes per bucket)
#define HIST_BLOCKS 128         // cg stays 128KB

typedef _Float16 h2   __attribute__((ext_vector_type(2)));   // packed f16 pair
typedef _Float16 f16x8 __attribute__((ext_vector_type(8)));  // MFMA f16 fragment (4 VGPR)
typedef float  facc4 __attribute__((ext_vector_type(4)));    // 4 x f32

// ---------------- f16 helpers ----------------

__device__ __forceinline__ unsigned short f2h_bits(float f) {
    union { _Float16 h; unsigned short s; } c;
    c.h = (_Float16)f;
    return c.s;
}

__device__ __forceinline__ unsigned int pkh(float lo, float hi) {
    return (unsigned int)f2h_bits(lo) | ((unsigned int)f2h_bits(hi) << 16);
}

__device__ __forceinline__ h2 u2h(unsigned int u) {
    union { unsigned int u; h2 h; } c; c.u = u; return c.h;
}

__device__ __forceinline__ unsigned int h2u(h2 h) {
    union { unsigned int u; h2 h; } c; c.h = h; return c.u;
}

__device__ __forceinline__ void addpk16(h2* acc, uint4 r) {
    acc[0] += u2h(r.x);
    acc[1] += u2h(r.y);
    acc[2] += u2h(r.z);
    acc[3] += u2h(r.w);
}

// ---------------- two-level counting sort by dst ----------------

__global__ __launch_bounds__(256) void coarse_hist_kernel(const int* __restrict__ dst,
                                                          int* __restrict__ cg, int E) {
    __shared__ int h[NBKT_MAX];
    int tid = threadIdx.x;
    if (tid < NBKT_MAX) h[tid] = 0;
    __syncthreads();
    for (int e = blockIdx.x * 256 + tid; e < E; e += gridDim.x * 256)
        atomicAdd(&h[dst[e] >> BKT_SH], 1);
    __syncthreads();
    if (tid < NBKT_MAX) cg[blockIdx.x * NBKT_MAX + tid] = h[tid];
}

// ---------------- merged setup: scan (block 0) + BN fold (blocks 1-3) + weight pack ----------------

struct PrepArgs {
    const float *b, *g, *be, *m, *v;
    float *sc, *sh;
};

__global__ __launch_bounds__(256) void setup_kernel(const int* __restrict__ cg,
                                                    int* __restrict__ bucket_base,
                                                    int* __restrict__ bucket_cursor,
                                                    PrepArgs a0, PrepArgs a1, PrepArgs a2,
                                                    const float* __restrict__ W1,
                                                    const float* __restrict__ W2,
                                                    const float* __restrict__ W3,
                                                    unsigned short* __restrict__ o1,
                                                    unsigned short* __restrict__ o2,
                                                    unsigned short* __restrict__ o3) {
    int bid = blockIdx.x;
    int t = threadIdx.x;
    if (bid == 0) {
        __shared__ int h[NBKT_MAX];
        __shared__ int total;
        if (t < NBKT_MAX) {
            int s = 0;
            for (int b = 0; b < HIST_BLOCKS; ++b) s += cg[b * NBKT_MAX + t];
            h[t] = s;
        }
        __syncthreads();
        if (t == 0) {
            int run = 0;
            for (int i = 0; i < NBKT_MAX; ++i) { int c = h[i]; h[i] = run; run += c; }
            total = run;
        }
        __syncthreads();
        if (t < NBKT_MAX) {
            bucket_base[t] = h[t];
            bucket_cursor[t] = h[t];
        }
        if (t == 0) bucket_base[NBKT_MAX] = total;
    } else if (bid <= 3) {
        PrepArgs a = (bid == 1) ? a0 : (bid == 2) ? a1 : a2;
        if (t < HDIM) {
            float s = a.g[t] * rsqrtf(a.v[t] + BN_EPS);
            a.sc[t] = s;
            a.sh[t] = (a.b[t] - a.m[t]) * s + a.be[t];
        }
    } else {
        int i = (bid - 4) * 256 + t;     // packed index over all three weights
        const float* W;
        unsigned short* o;
        if (i < 128 * 160)                 { W = W1; o = o1; }
        else if (i < 128 * 160 + 160 * 160) { W = W2; o = o2; i -= 128 * 160; }
        else if (i < 128 * 160 + 2 * 160 * 160) { W = W3; o = o3; i -= 128 * 160 + 160 * 160; }
        else return;
        int j = i & 7;
        int l = (i >> 3) & 63;
        int u = (i >> 9) % 10;
        int tt = i / 5120;
        int k = tt * 32 + (l >> 4) * 8 + j;
        int nn = u * 16 + (l & 15);
        o[i] = f2h_bits(W[k * 160 + nn]);
    }
}

// level 1: partition packed (src<<8 | dst&255) into coarse-bucket-contiguous regions
__global__ __launch_bounds__(256) void part_kernel(const int* __restrict__ src,
                                                   const int* __restrict__ dst,
                                                   int* __restrict__ bucket_cursor,
                                                   unsigned int* __restrict__ pairs, int E) {
    __shared__ int bcnt[NBKT_MAX], bbase[NBKT_MAX], lc[NBKT_MAX];
    int tid = threadIdx.x;
    int per = (E + gridDim.x - 1) / gridDim.x;
    int beg = blockIdx.x * per;
    int end = min(beg + per, E);
    if (tid < NBKT_MAX) { bcnt[tid] = 0; lc[tid] = 0; }
    __syncthreads();
    for (int e = beg + tid; e < end; e += 256)
        atomicAdd(&bcnt[dst[e] >> BKT_SH], 1);
    __syncthreads();
    if (tid < NBKT_MAX)
        bbase[tid] = bcnt[tid] ? atomicAdd(&bucket_cursor[tid], bcnt[tid]) : 0;
    __syncthreads();
    for (int e = beg + tid; e < end; e += 256) {
        int d = dst[e];
        int b = d >> BKT_SH;
        int pos = bbase[b] + atomicAdd(&lc[b], 1);
        pairs[pos] = ((unsigned int)src[e] << BKT_SH) | (unsigned int)(d & (NBKT_MAX - 1));
    }
}

// level 2: per-bucket exact CSR build + local scatter + fused x*inv f16 pre-scale
__global__ __launch_bounds__(1024) void bucket_csr_kernel(const unsigned int* __restrict__ pairs,
                                                          const int* __restrict__ bucket_base,
                                                          int* __restrict__ row_off,
                                                          float* __restrict__ inv,
                                                          int* __restrict__ ssrc,
                                                          const float* __restrict__ x,
                                                          unsigned short* __restrict__ xs,
                                                          int n) {
    __shared__ int h[NBKT_MAX];
    __shared__ int ws[4];
    __shared__ float sinv[NBKT_MAX];
    int tid = threadIdx.x;
    int b = blockIdx.x;
    int node0 = b << BKT_SH;
    int beg = bucket_base[b], end = bucket_base[b + 1];
    if (tid < NBKT_MAX) h[tid] = 0;
    __syncthreads();
    for (int j = beg + tid; j < end; j += 1024)
        atomicAdd(&h[pairs[j] & (NBKT_MAX - 1)], 1);
    __syncthreads();
    int cntv = (tid < NBKT_MAX) ? h[tid] : 0;
    __syncthreads();
    int lane = tid & 63, wid = tid >> 6;
    int incl = cntv;
    #pragma unroll
    for (int off = 1; off < 64; off <<= 1) {
        int u = __shfl_up(incl, off);
        if (lane >= off) incl += u;
    }
    if (tid < NBKT_MAX && lane == 63) ws[wid] = incl;
    __syncthreads();
    if (tid == 0) {
        int r = 0;
        #pragma unroll
        for (int i = 0; i < 4; ++i) { int t = ws[i]; ws[i] = r; r += t; }
    }
    __syncthreads();
    int excl = (tid < NBKT_MAX) ? (ws[wid] + incl - cntv) : 0;
    if (tid < NBKT_MAX) {
        float iv = rsqrtf((float)(cntv + 1));    // +1 = self loop
        int node = node0 + tid;
        if (node < n) {
            row_off[node] = beg + excl;
            inv[node] = iv;
        }
        sinv[tid] = iv;
        h[tid] = excl;
    }
    if (tid == 0 && (node0 + NBKT_MAX) >= n) row_off[n] = end;
    __syncthreads();
    for (int j = beg + tid; j < end; j += 1024) {
        unsigned int p = pairs[j];
        int pos = beg + atomicAdd(&h[p & (NBKT_MAX - 1)], 1);
        ssrc[pos] = (int)(p >> BKT_SH);
    }
    // fused pre-scale: xs[node] = f16(x[node] * inv[node]) for this bucket's nodes
    for (int idx = tid; idx < NBKT_MAX * 32; idx += 1024) {
        int nd = node0 + (idx >> 5);
        if (nd < n) {
            float w = sinv[idx >> 5];
            float4 v = ((const float4*)x)[(size_t)nd * 32 + (idx & 31)];
            ushort4 o;
            o.x = f2h_bits(v.x * w); o.y = f2h_bits(v.y * w);
            o.z = f2h_bits(v.z * w); o.w = f2h_bits(v.w * w);
            ((ushort4*)xs)[(size_t)nd * 32 + (idx & 31)] = o;
        }
    }
}

// ---------------- fused layer: grouped-gather agg (16 nodes) -> LDS -> MFMA GEMM ----------------
// One wave per block. Phase 1: wave aggregates 16 consecutive nodes (grouped gather,
// G groups of LPR lanes, 4/2/1 ladder) and writes the inv-scaled rows into the LDS
// A-tile. Phase 2: the same wave runs the 16-row x 160-col MFMA GEMM with B streamed
// from global (panel stays hot in every XCD L2). Eliminates the bufA round-trip
// (32 MB/layer) and 3 GEMM dispatch serializations.
// LDS row stride = CIN+8 ch: 16B-aligned rows, A-fragment ds_read_b128 hits the
// 8-access/bank minimum (start banks uniform over multiples of 4).

template <int CIN, int OUTMODE>
__global__ __launch_bounds__(64) void fused_layer_kernel(const unsigned short* __restrict__ in_s,
                                                         const float* __restrict__ inv,
                                                         const int* __restrict__ row_off,
                                                         const int* __restrict__ ssrc,
                                                         const unsigned short* __restrict__ Bp,
                                                         const float* __restrict__ sc,
                                                         const float* __restrict__ sh,
                                                         float* __restrict__ CoutF,
                                                         unsigned short* __restrict__ CoutB,
                                                         int n) {
    constexpr int LPR = CIN / 8;          // lanes per row (uint4 = 8 ch)
    constexpr int G   = 64 / LPR;         // concurrent edges per wave
    constexpr int RB  = CIN * 2;          // row bytes
    constexpr int KT  = CIN / 32;         // MFMA K-tiles
    constexpr int STR = CIN + 8;          // LDS row stride (ch)
    __shared__ unsigned short hrow[16][STR];

    int lane = threadIdx.x;
    int node0 = blockIdx.x * 16;
    int g  = lane / LPR;
    int cl = lane - g * LPR;
    bool act = g < G;
    int lb = cl * 16;
    const char* bptr = (const char*)in_s;

    // ---- phase 1: aggregate 16 nodes into LDS ----
    for (int i = 0; i < 16; ++i) {
        int node = node0 + i;
        if (node >= n) break;
        int beg = row_off[node], end = row_off[node + 1];

        h2 acc[4];
        #pragma unroll
        for (int k = 0; k < 4; ++k) acc[k] = (h2){(_Float16)0.f, (_Float16)0.f};

        if (g == 0) {   // self-loop term
            uint4 r = *(const uint4*)(bptr + (size_t)node * RB + lb);
            addpk16(acc, r);
        }

        int e = act ? beg + g : end;
        // 4-deep ladder (insurance for reduced wave count at 1-wave blocks)
        for (; e + 3 * G < end; e += 4 * G) {
            int s0 = ssrc[e],         s1 = ssrc[e + G];
            int s2 = ssrc[e + 2 * G], s3 = ssrc[e + 3 * G];
            uint4 r0 = *(const uint4*)(bptr + (size_t)s0 * RB + lb);
            uint4 r1 = *(const uint4*)(bptr + (size_t)s1 * RB + lb);
            uint4 r2 = *(const uint4*)(bptr + (size_t)s2 * RB + lb);
            uint4 r3 = *(const uint4*)(bptr + (size_t)s3 * RB + lb);
            addpk16(acc, r0); addpk16(acc, r1);
            addpk16(acc, r2); addpk16(acc, r3);
        }
        if (e + G < end) {
            int s0 = ssrc[e], s1 = ssrc[e + G];
            uint4 r0 = *(const uint4*)(bptr + (size_t)s0 * RB + lb);
            uint4 r1 = *(const uint4*)(bptr + (size_t)s1 * RB + lb);
            addpk16(acc, r0); addpk16(acc, r1);
            e += 2 * G;
        }
        if (e < end) {
            uint4 r = *(const uint4*)(bptr + (size_t)ssrc[e] * RB + lb);
            addpk16(acc, r);
        }

        // cross-group combine (packed f16)
        if (G == 4) {
            #pragma unroll
            for (int k = 0; k < 4; ++k) acc[k] += u2h(__shfl(h2u(acc[k]), lane + 32));
            #pragma unroll
            for (int k = 0; k < 4; ++k) acc[k] += u2h(__shfl(h2u(acc[k]), lane + 16));
        } else {
            #pragma unroll
            for (int k = 0; k < 4; ++k) {
                unsigned int ua = __shfl(h2u(acc[k]), lane + 20);
                unsigned int ub = __shfl(h2u(acc[k]), lane + 40);
                acc[k] += u2h(ua) + u2h(ub);
            }
        }

        if (lane < LPR) {
            float wi = inv[node];      // final deg-norm scale in fp32
            uint4 o;
            o.x = pkh((float)acc[0].x * wi, (float)acc[0].y * wi);
            o.y = pkh((float)acc[1].x * wi, (float)acc[1].y * wi);
            o.z = pkh((float)acc[2].x * wi, (float)acc[2].y * wi);
            o.w = pkh((float)acc[3].x * wi, (float)acc[3].y * wi);
            *(uint4*)&hrow[i][cl * 8] = o;
        }
    }
    __syncthreads();

    // ---- phase 2: 16-row x 160-col MFMA GEMM ----
    int m = lane & 15, q = lane >> 4;
    const f16x8* Bf = (const f16x8*)Bp;    // frag idx = (t*10+u)*64 + lane

    facc4 acc[10];
    #pragma unroll
    for (int u = 0; u < 10; ++u) acc[u] = (facc4){0.f, 0.f, 0.f, 0.f};

    #pragma unroll
    for (int t = 0; t < KT; ++t) {
        f16x8 af = *(const f16x8*)&hrow[m][t * 32 + q * 8];
        #pragma unroll
        for (int u = 0; u < 10; ++u) {
            f16x8 bf = Bf[(t * 10 + u) * 64 + lane];
            acc[u] = __builtin_amdgcn_mfma_f32_16x16x32_f16(af, bf, acc[u], 0, 0, 0);
        }
    }

    // D layout: col = lane&15 (within tile), row = q*4 + reg
    #pragma unroll
    for (int u = 0; u < 10; ++u) {
        int c = u * 16 + m;
        float scv = sc[c], shv = sh[c];
        #pragma unroll
        for (int r = 0; r < 4; ++r) {
            int rr = node0 + q * 4 + r;
            if (rr < n) {
                float v = fmaxf(acc[u][r] * scv + shv, 0.f);
                if (OUTMODE == 1) CoutB[(size_t)rr * 160 + c] = f2h_bits(v * inv[rr]);
                else              CoutF[(size_t)rr * 160 + c] = v;
            }
        }
    }
}

// ---------------- mean pool (sorted batch) + MLP head ----------------

__global__ __launch_bounds__(256) void pool_head_kernel(const float* __restrict__ h,
                                                        const int* __restrict__ batch,
                                                        const float* __restrict__ Wc1,
                                                        const float* __restrict__ bc1,
                                                        const float* __restrict__ Wc2,
                                                        const float* __restrict__ bc2,
                                                        float* __restrict__ out, int n) {
    __shared__ float4 part[6][40];
    __shared__ float pooled[160];
    __shared__ float z[80];
    __shared__ int range[2];
    int g = blockIdx.x;
    int t = threadIdx.x;
    if (t < 2) {
        int target = g + t;
        int lo = 0, hi = n;
        while (lo < hi) {
            int mid = (lo + hi) >> 1;
            if (batch[mid] < target) lo = mid + 1; else hi = mid;
        }
        range[t] = lo;
    }
    __syncthreads();
    int lo = range[0], hi = range[1];
    int sub = t / 40, c4 = t - sub * 40;
    if (sub < 6) {
        float4 a = {0.f, 0.f, 0.f, 0.f};
        for (int r = lo + sub; r < hi; r += 6) {
            float4 v = ((const float4*)(h + (size_t)r * 160))[c4];
            a.x += v.x; a.y += v.y; a.z += v.z; a.w += v.w;
        }
        part[sub][c4] = a;
    }
    __syncthreads();
    if (t < 40) {
        float4 s = {0.f, 0.f, 0.f, 0.f};
        #pragma unroll
        for (int i = 0; i < 6; ++i) {
            float4 p = part[i][t];
            s.x += p.x; s.y += p.y; s.z += p.z; s.w += p.w;
        }
        float ic = 1.f / fmaxf((float)(hi - lo), 1.f);
        pooled[t * 4 + 0] = s.x * ic;
        pooled[t * 4 + 1] = s.y * ic;
        pooled[t * 4 + 2] = s.z * ic;
        pooled[t * 4 + 3] = s.w * ic;
    }
    __syncthreads();
    if (t < 80) {
        float s = bc1[t];
        for (int k = 0; k < 160; ++k) s += pooled[k] * Wc1[k * 80 + t];
        z[t] = fmaxf(s, 0.f);
    }
    __syncthreads();
    if (t < 2) {
        float s = bc2[t];
        for (int k = 0; k < 80; ++k) s += z[k] * Wc2[k * 2 + t];
        out[g * 2 + t] = s;
    }
}

// ---------------- launch ----------------

static inline size_t align256(size_t x) { return (x + 255) & ~(size_t)255; }

extern "C" void kernel_launch(void* const* d_in, const int* in_sizes, int n_in,
                              void* d_out, int out_size, void* d_ws, size_t ws_size,
                              hipStream_t stream) {
    const float* x   = (const float*)d_in[0];
    const int* ei    = (const int*)d_in[1];
    const int* batch = (const int*)d_in[2];
    const float* W1  = (const float*)d_in[3];
    const float* b1  = (const float*)d_in[4];
    const float* W2  = (const float*)d_in[5];
    const float* b2  = (const float*)d_in[6];
    const float* W3  = (const float*)d_in[7];
    const float* b3  = (const float*)d_in[8];
    const float* g1  = (const float*)d_in[9];
    const float* be1 = (const float*)d_in[10];
    const float* m1  = (const float*)d_in[11];
    const float* v1  = (const float*)d_in[12];
    const float* g2  = (const float*)d_in[13];
    const float* be2 = (const float*)d_in[14];
    const float* m2  = (const float*)d_in[15];
    const float* v2  = (const float*)d_in[16];
    const float* g3  = (const float*)d_in[17];
    const float* be3 = (const float*)d_in[18];
    const float* m3  = (const float*)d_in[19];
    const float* v3  = (const float*)d_in[20];
    const float* Wc1 = (const float*)d_in[21];
    const float* bc1 = (const float*)d_in[22];
    const float* Wc2 = (const float*)d_in[23];
    const float* bc2 = (const float*)d_in[24];
    float* out = (float*)d_out;

    const int N = in_sizes[2];          // 50000
    const int E = in_sizes[1] / 2;      // 1600000
    const int* src = ei;
    const int* dst = ei + E;

    char* w = (char*)d_ws;
    int*   row_off = (int*)w;             w += align256((size_t)(N + 1) * 4);
    float* inv     = (float*)w;           w += align256((size_t)N * 4);
    int*   ssrc    = (int*)w;             w += align256((size_t)E * 4);
    unsigned int* pairs = (unsigned int*)w; w += align256((size_t)E * 4);
    int*   cg      = (int*)w;             w += align256((size_t)HIST_BLOCKS * NBKT_MAX * 4);
    int*   bucket_base   = (int*)w;       w += align256((size_t)(NBKT_MAX + 1) * 4);
    int*   bucket_cursor = (int*)w;       w += align256((size_t)NBKT_MAX * 4);
    float* scsh    = (float*)w;           w += align256((size_t)6 * HDIM * 4);
    unsigned short* W1p = (unsigned short*)w;  w += align256((size_t)FDIM_IN * HDIM * 2);
    unsigned short* W2p = (unsigned short*)w;  w += align256((size_t)HDIM * HDIM * 2);
    unsigned short* W3p = (unsigned short*)w;  w += align256((size_t)HDIM * HDIM * 2);
    unsigned short* xs_bf  = (unsigned short*)w;  w += align256((size_t)N * FDIM_IN * 2);
    unsigned short* h1_bf  = (unsigned short*)w;  w += align256((size_t)N * HDIM * 2);
    unsigned short* h2_bf  = (unsigned short*)w;  w += align256((size_t)N * HDIM * 2);
    float* bufC    = (float*)w;           w += align256((size_t)N * HDIM * 4);
    float* sc1 = scsh, *sh1 = scsh + 160, *sc2 = scsh + 320, *sh2 = scsh + 480,
         * sc3 = scsh + 640, *sh3 = scsh + 800;

    // two-level counting sort by dst -> row_off, ssrc, inv (+ fused x pre-scale)
    coarse_hist_kernel<<<HIST_BLOCKS, 256, 0, stream>>>(dst, cg, E);

    PrepArgs pa0 = {b1, g1, be1, m1, v1, sc1, sh1};
    PrepArgs pa1 = {b2, g2, be2, m2, v2, sc2, sh2};
    PrepArgs pa2 = {b3, g3, be3, m3, v3, sc3, sh3};
    int packTotal = 128 * 160 + 2 * 160 * 160;
    int setupBlocks = 4 + (packTotal + 255) / 256;
    setup_kernel<<<setupBlocks, 256, 0, stream>>>(cg, bucket_base, bucket_cursor,
                                                  pa0, pa1, pa2, W1, W2, W3, W1p, W2p, W3p);

    part_kernel<<<256, 256, 0, stream>>>(src, dst, bucket_cursor, pairs, E);
    int nbkt = (N + NBKT_MAX - 1) >> BKT_SH;
    bucket_csr_kernel<<<nbkt, 1024, 0, stream>>>(pairs, bucket_base, row_off, inv, ssrc, x, xs_bf, N);

    int gF = (N + 15) / 16;

    // fused agg+GEMM per layer (ping-pong buffers, no aliasing)
    fused_layer_kernel<128, 1><<<gF, 64, 0, stream>>>(xs_bf, inv, row_off, ssrc, W1p, sc1, sh1, nullptr, h1_bf, N);
    fused_layer_kernel<160, 1><<<gF, 64, 0, stream>>>(h1_bf, inv, row_off, ssrc, W2p, sc2, sh2, nullptr, h2_bf, N);
    fused_layer_kernel<160, 0><<<gF, 64, 0, stream>>>(h2_bf, inv, row_off, ssrc, W3p, sc3, sh3, bufC, nullptr, N);

    pool_head_kernel<<<N_GRAPHS, 256, 0, stream>>>(bufC, batch, Wc1, bc1, Wc2, bc2, out, N);
}

// Round 11
// 418.300 us; speedup vs baseline: 1.1476x; 1.0220x over previous
//
#include <hip/hip_runtime.h>

#define N_NODES   50000
#define N_EDGES   1600000
#define FDIM_IN   128
#define HDIM      160
#define N_GRAPHS  512
#define BN_EPS    1e-5f
#define NBKT_MAX  256           // coarse buckets of 256 nodes (N<=65536)
#define BKT_SH    8             // log2(nodes per bucket)
#define HIST_BLOCKS 128         // cg stays 128KB

typedef _Float16 h2   __attribute__((ext_vector_type(2)));   // packed f16 pair
typedef _Float16 f16x8 __attribute__((ext_vector_type(8)));  // MFMA f16 fragment (4 VGPR)
typedef float  facc4 __attribute__((ext_vector_type(4)));    // 4 x f32

// ---------------- f16 helpers ----------------

__device__ __forceinline__ unsigned short f2h_bits(float f) {
    union { _Float16 h; unsigned short s; } c;
    c.h = (_Float16)f;
    return c.s;
}

__device__ __forceinline__ unsigned int pkh(float lo, float hi) {
    return (unsigned int)f2h_bits(lo) | ((unsigned int)f2h_bits(hi) << 16);
}

__device__ __forceinline__ h2 u2h(unsigned int u) {
    union { unsigned int u; h2 h; } c; c.u = u; return c.h;
}

__device__ __forceinline__ unsigned int h2u(h2 h) {
    union { unsigned int u; h2 h; } c; c.h = h; return c.u;
}

__device__ __forceinline__ void addpk16(h2* acc, uint4 r) {
    acc[0] += u2h(r.x);
    acc[1] += u2h(r.y);
    acc[2] += u2h(r.z);
    acc[3] += u2h(r.w);
}

// ---------------- two-level counting sort by dst ----------------

__global__ __launch_bounds__(256) void coarse_hist_kernel(const int* __restrict__ dst,
                                                          int* __restrict__ cg, int E) {
    __shared__ int h[NBKT_MAX];
    int tid = threadIdx.x;
    if (tid < NBKT_MAX) h[tid] = 0;
    __syncthreads();
    for (int e = blockIdx.x * 256 + tid; e < E; e += gridDim.x * 256)
        atomicAdd(&h[dst[e] >> BKT_SH], 1);
    __syncthreads();
    if (tid < NBKT_MAX) cg[blockIdx.x * NBKT_MAX + tid] = h[tid];
}

// ---------------- merged setup: scan (block 0) + BN fold (blocks 1-3) + weight pack ----------------

struct PrepArgs {
    const float *b, *g, *be, *m, *v;
    float *sc, *sh;
};

__global__ __launch_bounds__(256) void setup_kernel(const int* __restrict__ cg,
                                                    int* __restrict__ bucket_base,
                                                    int* __restrict__ bucket_cursor,
                                                    PrepArgs a0, PrepArgs a1, PrepArgs a2,
                                                    const float* __restrict__ W1,
                                                    const float* __restrict__ W2,
                                                    const float* __restrict__ W3,
                                                    unsigned short* __restrict__ o1,
                                                    unsigned short* __restrict__ o2,
                                                    unsigned short* __restrict__ o3) {
    int bid = blockIdx.x;
    int t = threadIdx.x;
    if (bid == 0) {
        __shared__ int h[NBKT_MAX];
        __shared__ int total;
        if (t < NBKT_MAX) {
            int s = 0;
            for (int b = 0; b < HIST_BLOCKS; ++b) s += cg[b * NBKT_MAX + t];
            h[t] = s;
        }
        __syncthreads();
        if (t == 0) {
            int run = 0;
            for (int i = 0; i < NBKT_MAX; ++i) { int c = h[i]; h[i] = run; run += c; }
            total = run;
        }
        __syncthreads();
        if (t < NBKT_MAX) {
            bucket_base[t] = h[t];
            bucket_cursor[t] = h[t];
        }
        if (t == 0) bucket_base[NBKT_MAX] = total;
    } else if (bid <= 3) {
        PrepArgs a = (bid == 1) ? a0 : (bid == 2) ? a1 : a2;
        if (t < HDIM) {
            float s = a.g[t] * rsqrtf(a.v[t] + BN_EPS);
            a.sc[t] = s;
            a.sh[t] = (a.b[t] - a.m[t]) * s + a.be[t];
        }
    } else {
        int i = (bid - 4) * 256 + t;     // packed index over all three weights
        const float* W;
        unsigned short* o;
        if (i < 128 * 160)                 { W = W1; o = o1; }
        else if (i < 128 * 160 + 160 * 160) { W = W2; o = o2; i -= 128 * 160; }
        else if (i < 128 * 160 + 2 * 160 * 160) { W = W3; o = o3; i -= 128 * 160 + 160 * 160; }
        else return;
        int j = i & 7;
        int l = (i >> 3) & 63;
        int u = (i >> 9) % 10;
        int tt = i / 5120;
        int k = tt * 32 + (l >> 4) * 8 + j;
        int nn = u * 16 + (l & 15);
        o[i] = f2h_bits(W[k * 160 + nn]);
    }
}

// level 1: partition packed (src<<8 | dst&255) into coarse-bucket-contiguous regions
__global__ __launch_bounds__(256) void part_kernel(const int* __restrict__ src,
                                                   const int* __restrict__ dst,
                                                   int* __restrict__ bucket_cursor,
                                                   unsigned int* __restrict__ pairs, int E) {
    __shared__ int bcnt[NBKT_MAX], bbase[NBKT_MAX], lc[NBKT_MAX];
    int tid = threadIdx.x;
    int per = (E + gridDim.x - 1) / gridDim.x;
    int beg = blockIdx.x * per;
    int end = min(beg + per, E);
    if (tid < NBKT_MAX) { bcnt[tid] = 0; lc[tid] = 0; }
    __syncthreads();
    for (int e = beg + tid; e < end; e += 256)
        atomicAdd(&bcnt[dst[e] >> BKT_SH], 1);
    __syncthreads();
    if (tid < NBKT_MAX)
        bbase[tid] = bcnt[tid] ? atomicAdd(&bucket_cursor[tid], bcnt[tid]) : 0;
    __syncthreads();
    for (int e = beg + tid; e < end; e += 256) {
        int d = dst[e];
        int b = d >> BKT_SH;
        int pos = bbase[b] + atomicAdd(&lc[b], 1);
        pairs[pos] = ((unsigned int)src[e] << BKT_SH) | (unsigned int)(d & (NBKT_MAX - 1));
    }
}

// level 2: per-bucket exact CSR build + local scatter + fused x*inv f16 pre-scale
__global__ __launch_bounds__(1024) void bucket_csr_kernel(const unsigned int* __restrict__ pairs,
                                                          const int* __restrict__ bucket_base,
                                                          int* __restrict__ row_off,
                                                          float* __restrict__ inv,
                                                          int* __restrict__ ssrc,
                                                          const float* __restrict__ x,
                                                          unsigned short* __restrict__ xs,
                                                          int n) {
    __shared__ int h[NBKT_MAX];
    __shared__ int ws[4];
    __shared__ float sinv[NBKT_MAX];
    int tid = threadIdx.x;
    int b = blockIdx.x;
    int node0 = b << BKT_SH;
    int beg = bucket_base[b], end = bucket_base[b + 1];
    if (tid < NBKT_MAX) h[tid] = 0;
    __syncthreads();
    for (int j = beg + tid; j < end; j += 1024)
        atomicAdd(&h[pairs[j] & (NBKT_MAX - 1)], 1);
    __syncthreads();
    int cntv = (tid < NBKT_MAX) ? h[tid] : 0;
    __syncthreads();
    int lane = tid & 63, wid = tid >> 6;
    int incl = cntv;
    #pragma unroll
    for (int off = 1; off < 64; off <<= 1) {
        int u = __shfl_up(incl, off);
        if (lane >= off) incl += u;
    }
    if (tid < NBKT_MAX && lane == 63) ws[wid] = incl;
    __syncthreads();
    if (tid == 0) {
        int r = 0;
        #pragma unroll
        for (int i = 0; i < 4; ++i) { int t = ws[i]; ws[i] = r; r += t; }
    }
    __syncthreads();
    int excl = (tid < NBKT_MAX) ? (ws[wid] + incl - cntv) : 0;
    if (tid < NBKT_MAX) {
        float iv = rsqrtf((float)(cntv + 1));    // +1 = self loop
        int node = node0 + tid;
        if (node < n) {
            row_off[node] = beg + excl;
            inv[node] = iv;
        }
        sinv[tid] = iv;
        h[tid] = excl;
    }
    if (tid == 0 && (node0 + NBKT_MAX) >= n) row_off[n] = end;
    __syncthreads();
    for (int j = beg + tid; j < end; j += 1024) {
        unsigned int p = pairs[j];
        int pos = beg + atomicAdd(&h[p & (NBKT_MAX - 1)], 1);
        ssrc[pos] = (int)(p >> BKT_SH);
    }
    // fused pre-scale: xs[node] = f16(x[node] * inv[node]) for this bucket's nodes
    for (int idx = tid; idx < NBKT_MAX * 32; idx += 1024) {
        int nd = node0 + (idx >> 5);
        if (nd < n) {
            float w = sinv[idx >> 5];
            float4 v = ((const float4*)x)[(size_t)nd * 32 + (idx & 31)];
            ushort4 o;
            o.x = f2h_bits(v.x * w); o.y = f2h_bits(v.y * w);
            o.z = f2h_bits(v.z * w); o.w = f2h_bits(v.w * w);
            ((ushort4*)xs)[(size_t)nd * 32 + (idx & 31)] = o;
        }
    }
}

// ---------------- fused layer v2: 4-wave block, agg 16 nodes -> LDS -> split MFMA GEMM ----------------
// 256 threads = 4 waves. Phase 1: wave w aggregates nodes node0+w*4+i (i=0..3) --
// identical per-wave structure to the standalone agg kernel (R8: 70.6us floor),
// restoring occupancy lost by R10's 1-wave blocks (30% -> ~65%). Phase 2: waves
// split the 10 column-tiles of the 16x160 GEMM (u = w, w+4, w+8); A from shared
// LDS tile, B streamed from global (L2-hot). Tail rows zero-filled (no NaN feed).

template <int CIN, int OUTMODE>
__global__ __launch_bounds__(256) void fused_layer_kernel(const unsigned short* __restrict__ in_s,
                                                          const float* __restrict__ inv,
                                                          const int* __restrict__ row_off,
                                                          const int* __restrict__ ssrc,
                                                          const unsigned short* __restrict__ Bp,
                                                          const float* __restrict__ sc,
                                                          const float* __restrict__ sh,
                                                          float* __restrict__ CoutF,
                                                          unsigned short* __restrict__ CoutB,
                                                          int n) {
    constexpr int LPR = CIN / 8;          // lanes per row (uint4 = 8 ch)
    constexpr int G   = 64 / LPR;         // concurrent edges per wave
    constexpr int RB  = CIN * 2;          // row bytes
    constexpr int KT  = CIN / 32;         // MFMA K-tiles
    constexpr int STR = CIN + 8;          // LDS row stride (ch)
    __shared__ unsigned short hrow[16][STR];

    int tid  = threadIdx.x;
    int wv   = tid >> 6;
    int lane = tid & 63;
    int node0 = blockIdx.x * 16;
    int g  = lane / LPR;
    int cl = lane - g * LPR;
    bool act = g < G;
    int lb = cl * 16;
    const char* bptr = (const char*)in_s;

    // ---- phase 1: each wave aggregates its 4 nodes into the shared LDS A-tile ----
    for (int i = 0; i < 4; ++i) {
        int row = wv * 4 + i;
        int node = node0 + row;
        if (node >= n) {
            if (lane < LPR) {
                uint4 z = {0u, 0u, 0u, 0u};
                *(uint4*)&hrow[row][cl * 8] = z;
            }
            continue;
        }
        int beg = row_off[node], end = row_off[node + 1];

        h2 acc[4];
        #pragma unroll
        for (int k = 0; k < 4; ++k) acc[k] = (h2){(_Float16)0.f, (_Float16)0.f};

        if (g == 0) {   // self-loop term
            uint4 r = *(const uint4*)(bptr + (size_t)node * RB + lb);
            addpk16(acc, r);
        }

        int e = act ? beg + g : end;
        for (; e + G < end; e += 2 * G) {
            int s0 = ssrc[e], s1 = ssrc[e + G];
            uint4 r0 = *(const uint4*)(bptr + (size_t)s0 * RB + lb);
            uint4 r1 = *(const uint4*)(bptr + (size_t)s1 * RB + lb);
            addpk16(acc, r0);
            addpk16(acc, r1);
        }
        if (e < end) {
            uint4 r = *(const uint4*)(bptr + (size_t)ssrc[e] * RB + lb);
            addpk16(acc, r);
        }

        // cross-group combine (packed f16)
        if (G == 4) {
            #pragma unroll
            for (int k = 0; k < 4; ++k) acc[k] += u2h(__shfl(h2u(acc[k]), lane + 32));
            #pragma unroll
            for (int k = 0; k < 4; ++k) acc[k] += u2h(__shfl(h2u(acc[k]), lane + 16));
        } else {
            #pragma unroll
            for (int k = 0; k < 4; ++k) {
                unsigned int ua = __shfl(h2u(acc[k]), lane + 20);
                unsigned int ub = __shfl(h2u(acc[k]), lane + 40);
                acc[k] += u2h(ua) + u2h(ub);
            }
        }

        if (lane < LPR) {
            float wi = inv[node];      // final deg-norm scale in fp32
            uint4 o;
            o.x = pkh((float)acc[0].x * wi, (float)acc[0].y * wi);
            o.y = pkh((float)acc[1].x * wi, (float)acc[1].y * wi);
            o.z = pkh((float)acc[2].x * wi, (float)acc[2].y * wi);
            o.w = pkh((float)acc[3].x * wi, (float)acc[3].y * wi);
            *(uint4*)&hrow[row][cl * 8] = o;
        }
    }
    __syncthreads();

    // ---- phase 2: 16x160 MFMA GEMM, column-tiles split across the 4 waves ----
    int m = lane & 15, q = lane >> 4;
    const f16x8* Bf = (const f16x8*)Bp;    // frag idx = (t*10+u)*64 + lane

    f16x8 afr[KT];
    #pragma unroll
    for (int t = 0; t < KT; ++t) afr[t] = *(const f16x8*)&hrow[m][t * 32 + q * 8];

    for (int u = wv; u < 10; u += 4) {
        facc4 acc = (facc4){0.f, 0.f, 0.f, 0.f};
        #pragma unroll
        for (int t = 0; t < KT; ++t) {
            f16x8 bf = Bf[(t * 10 + u) * 64 + lane];
            acc = __builtin_amdgcn_mfma_f32_16x16x32_f16(afr[t], bf, acc, 0, 0, 0);
        }
        // D layout: col = lane&15 (within tile), row = q*4 + reg
        int c = u * 16 + m;
        float scv = sc[c], shv = sh[c];
        #pragma unroll
        for (int r = 0; r < 4; ++r) {
            int rr = node0 + q * 4 + r;
            if (rr < n) {
                float v = fmaxf(acc[r] * scv + shv, 0.f);
                if (OUTMODE == 1) CoutB[(size_t)rr * 160 + c] = f2h_bits(v * inv[rr]);
                else              CoutF[(size_t)rr * 160 + c] = v;
            }
        }
    }
}

// ---------------- mean pool (sorted batch) + MLP head ----------------

__global__ __launch_bounds__(256) void pool_head_kernel(const float* __restrict__ h,
                                                        const int* __restrict__ batch,
                                                        const float* __restrict__ Wc1,
                                                        const float* __restrict__ bc1,
                                                        const float* __restrict__ Wc2,
                                                        const float* __restrict__ bc2,
                                                        float* __restrict__ out, int n) {
    __shared__ float4 part[6][40];
    __shared__ float pooled[160];
    __shared__ float z[80];
    __shared__ int range[2];
    int g = blockIdx.x;
    int t = threadIdx.x;
    if (t < 2) {
        int target = g + t;
        int lo = 0, hi = n;
        while (lo < hi) {
            int mid = (lo + hi) >> 1;
            if (batch[mid] < target) lo = mid + 1; else hi = mid;
        }
        range[t] = lo;
    }
    __syncthreads();
    int lo = range[0], hi = range[1];
    int sub = t / 40, c4 = t - sub * 40;
    if (sub < 6) {
        float4 a = {0.f, 0.f, 0.f, 0.f};
        for (int r = lo + sub; r < hi; r += 6) {
            float4 v = ((const float4*)(h + (size_t)r * 160))[c4];
            a.x += v.x; a.y += v.y; a.z += v.z; a.w += v.w;
        }
        part[sub][c4] = a;
    }
    __syncthreads();
    if (t < 40) {
        float4 s = {0.f, 0.f, 0.f, 0.f};
        #pragma unroll
        for (int i = 0; i < 6; ++i) {
            float4 p = part[i][t];
            s.x += p.x; s.y += p.y; s.z += p.z; s.w += p.w;
        }
        float ic = 1.f / fmaxf((float)(hi - lo), 1.f);
        pooled[t * 4 + 0] = s.x * ic;
        pooled[t * 4 + 1] = s.y * ic;
        pooled[t * 4 + 2] = s.z * ic;
        pooled[t * 4 + 3] = s.w * ic;
    }
    __syncthreads();
    if (t < 80) {
        float s = bc1[t];
        for (int k = 0; k < 160; ++k) s += pooled[k] * Wc1[k * 80 + t];
        z[t] = fmaxf(s, 0.f);
    }
    __syncthreads();
    if (t < 2) {
        float s = bc2[t];
        for (int k = 0; k < 80; ++k) s += z[k] * Wc2[k * 2 + t];
        out[g * 2 + t] = s;
    }
}

// ---------------- launch ----------------

static inline size_t align256(size_t x) { return (x + 255) & ~(size_t)255; }

extern "C" void kernel_launch(void* const* d_in, const int* in_sizes, int n_in,
                              void* d_out, int out_size, void* d_ws, size_t ws_size,
                              hipStream_t stream) {
    const float* x   = (const float*)d_in[0];
    const int* ei    = (const int*)d_in[1];
    const int* batch = (const int*)d_in[2];
    const float* W1  = (const float*)d_in[3];
    const float* b1  = (const float*)d_in[4];
    const float* W2  = (const float*)d_in[5];
    const float* b2  = (const float*)d_in[6];
    const float* W3  = (const float*)d_in[7];
    const float* b3  = (const float*)d_in[8];
    const float* g1  = (const float*)d_in[9];
    const float* be1 = (const float*)d_in[10];
    const float* m1  = (const float*)d_in[11];
    const float* v1  = (const float*)d_in[12];
    const float* g2  = (const float*)d_in[13];
    const float* be2 = (const float*)d_in[14];
    const float* m2  = (const float*)d_in[15];
    const float* v2  = (const float*)d_in[16];
    const float* g3  = (const float*)d_in[17];
    const float* be3 = (const float*)d_in[18];
    const float* m3  = (const float*)d_in[19];
    const float* v3  = (const float*)d_in[20];
    const float* Wc1 = (const float*)d_in[21];
    const float* bc1 = (const float*)d_in[22];
    const float* Wc2 = (const float*)d_in[23];
    const float* bc2 = (const float*)d_in[24];
    float* out = (float*)d_out;

    const int N = in_sizes[2];          // 50000
    const int E = in_sizes[1] / 2;      // 1600000
    const int* src = ei;
    const int* dst = ei + E;

    char* w = (char*)d_ws;
    int*   row_off = (int*)w;             w += align256((size_t)(N + 1) * 4);
    float* inv     = (float*)w;           w += align256((size_t)N * 4);
    int*   ssrc    = (int*)w;             w += align256((size_t)E * 4);
    unsigned int* pairs = (unsigned int*)w; w += align256((size_t)E * 4);
    int*   cg      = (int*)w;             w += align256((size_t)HIST_BLOCKS * NBKT_MAX * 4);
    int*   bucket_base   = (int*)w;       w += align256((size_t)(NBKT_MAX + 1) * 4);
    int*   bucket_cursor = (int*)w;       w += align256((size_t)NBKT_MAX * 4);
    float* scsh    = (float*)w;           w += align256((size_t)6 * HDIM * 4);
    unsigned short* W1p = (unsigned short*)w;  w += align256((size_t)FDIM_IN * HDIM * 2);
    unsigned short* W2p = (unsigned short*)w;  w += align256((size_t)HDIM * HDIM * 2);
    unsigned short* W3p = (unsigned short*)w;  w += align256((size_t)HDIM * HDIM * 2);
    unsigned short* xs_bf  = (unsigned short*)w;  w += align256((size_t)N * FDIM_IN * 2);
    unsigned short* h1_bf  = (unsigned short*)w;  w += align256((size_t)N * HDIM * 2);
    unsigned short* h2_bf  = (unsigned short*)w;  w += align256((size_t)N * HDIM * 2);
    float* bufC    = (float*)w;           w += align256((size_t)N * HDIM * 4);
    float* sc1 = scsh, *sh1 = scsh + 160, *sc2 = scsh + 320, *sh2 = scsh + 480,
         * sc3 = scsh + 640, *sh3 = scsh + 800;

    // two-level counting sort by dst -> row_off, ssrc, inv (+ fused x pre-scale)
    coarse_hist_kernel<<<HIST_BLOCKS, 256, 0, stream>>>(dst, cg, E);

    PrepArgs pa0 = {b1, g1, be1, m1, v1, sc1, sh1};
    PrepArgs pa1 = {b2, g2, be2, m2, v2, sc2, sh2};
    PrepArgs pa2 = {b3, g3, be3, m3, v3, sc3, sh3};
    int packTotal = 128 * 160 + 2 * 160 * 160;
    int setupBlocks = 4 + (packTotal + 255) / 256;
    setup_kernel<<<setupBlocks, 256, 0, stream>>>(cg, bucket_base, bucket_cursor,
                                                  pa0, pa1, pa2, W1, W2, W3, W1p, W2p, W3p);

    part_kernel<<<256, 256, 0, stream>>>(src, dst, bucket_cursor, pairs, E);
    int nbkt = (N + NBKT_MAX - 1) >> BKT_SH;
    bucket_csr_kernel<<<nbkt, 1024, 0, stream>>>(pairs, bucket_base, row_off, inv, ssrc, x, xs_bf, N);

    int gF = (N + 15) / 16;

    // fused agg+GEMM per layer (ping-pong buffers, no aliasing)
    fused_layer_kernel<128, 1><<<gF, 256, 0, stream>>>(xs_bf, inv, row_off, ssrc, W1p, sc1, sh1, nullptr, h1_bf, N);
    fused_layer_kernel<160, 1><<<gF, 256, 0, stream>>>(h1_bf, inv, row_off, ssrc, W2p, sc2, sh2, nullptr, h2_bf, N);
    fused_layer_kernel<160, 0><<<gF, 256, 0, stream>>>(h2_bf, inv, row_off, ssrc, W3p, sc3, sh3, bufC, nullptr, N);

    pool_head_kernel<<<N_GRAPHS, 256, 0, stream>>>(bufC, batch, Wc1, bc1, Wc2, bc2, out, N);
}

// Round 12
// 415.983 us; speedup vs baseline: 1.1540x; 1.0056x over previous
//
#include <hip/hip_runtime.h>

#define N_NODES   50000
#define N_EDGES   1600000
#define FDIM_IN   128
#define HDIM      160
#define N_GRAPHS  512
#define BN_EPS    1e-5f
#define NBKT_MAX  256           // coarse buckets of 256 nodes (N<=65536)
#define BKT_SH    8             // log2(nodes per bucket)
#define HIST_BLOCKS 128         // cg stays 128KB

typedef _Float16 h2   __attribute__((ext_vector_type(2)));   // packed f16 pair
typedef _Float16 f16x8 __attribute__((ext_vector_type(8)));  // MFMA f16 fragment (4 VGPR)
typedef float  facc4 __attribute__((ext_vector_type(4)));    // 4 x f32

// ---------------- f16 helpers ----------------

__device__ __forceinline__ unsigned short f2h_bits(float f) {
    union { _Float16 h; unsigned short s; } c;
    c.h = (_Float16)f;
    return c.s;
}

__device__ __forceinline__ unsigned int pkh(float lo, float hi) {
    return (unsigned int)f2h_bits(lo) | ((unsigned int)f2h_bits(hi) << 16);
}

__device__ __forceinline__ h2 u2h(unsigned int u) {
    union { unsigned int u; h2 h; } c; c.u = u; return c.h;
}

__device__ __forceinline__ unsigned int h2u(h2 h) {
    union { unsigned int u; h2 h; } c; c.h = h; return c.u;
}

__device__ __forceinline__ void addpk16(h2* acc, uint4 r) {
    acc[0] += u2h(r.x);
    acc[1] += u2h(r.y);
    acc[2] += u2h(r.z);
    acc[3] += u2h(r.w);
}

// ---------------- two-level counting sort by dst ----------------

__global__ __launch_bounds__(256) void coarse_hist_kernel(const int* __restrict__ dst,
                                                          int* __restrict__ cg, int E) {
    __shared__ int h[NBKT_MAX];
    int tid = threadIdx.x;
    if (tid < NBKT_MAX) h[tid] = 0;
    __syncthreads();
    for (int e = blockIdx.x * 256 + tid; e < E; e += gridDim.x * 256)
        atomicAdd(&h[dst[e] >> BKT_SH], 1);
    __syncthreads();
    if (tid < NBKT_MAX) cg[blockIdx.x * NBKT_MAX + tid] = h[tid];
}

// ---------------- merged setup: scan (block 0) + BN fold (blocks 1-3) + weight pack ----------------

struct PrepArgs {
    const float *b, *g, *be, *m, *v;
    float *sc, *sh;
};

__global__ __launch_bounds__(256) void setup_kernel(const int* __restrict__ cg,
                                                    int* __restrict__ bucket_base,
                                                    int* __restrict__ bucket_cursor,
                                                    PrepArgs a0, PrepArgs a1, PrepArgs a2,
                                                    const float* __restrict__ W1,
                                                    const float* __restrict__ W2,
                                                    const float* __restrict__ W3,
                                                    unsigned short* __restrict__ o1,
                                                    unsigned short* __restrict__ o2,
                                                    unsigned short* __restrict__ o3) {
    int bid = blockIdx.x;
    int t = threadIdx.x;
    if (bid == 0) {
        __shared__ int h[NBKT_MAX];
        __shared__ int total;
        if (t < NBKT_MAX) {
            int s = 0;
            for (int b = 0; b < HIST_BLOCKS; ++b) s += cg[b * NBKT_MAX + t];
            h[t] = s;
        }
        __syncthreads();
        if (t == 0) {
            int run = 0;
            for (int i = 0; i < NBKT_MAX; ++i) { int c = h[i]; h[i] = run; run += c; }
            total = run;
        }
        __syncthreads();
        if (t < NBKT_MAX) {
            bucket_base[t] = h[t];
            bucket_cursor[t] = h[t];
        }
        if (t == 0) bucket_base[NBKT_MAX] = total;
    } else if (bid <= 3) {
        PrepArgs a = (bid == 1) ? a0 : (bid == 2) ? a1 : a2;
        if (t < HDIM) {
            float s = a.g[t] * rsqrtf(a.v[t] + BN_EPS);
            a.sc[t] = s;
            a.sh[t] = (a.b[t] - a.m[t]) * s + a.be[t];
        }
    } else {
        int i = (bid - 4) * 256 + t;     // packed index over all three weights
        const float* W;
        unsigned short* o;
        if (i < 128 * 160)                 { W = W1; o = o1; }
        else if (i < 128 * 160 + 160 * 160) { W = W2; o = o2; i -= 128 * 160; }
        else if (i < 128 * 160 + 2 * 160 * 160) { W = W3; o = o3; i -= 128 * 160 + 160 * 160; }
        else return;
        int j = i & 7;
        int l = (i >> 3) & 63;
        int u = (i >> 9) % 10;
        int tt = i / 5120;
        int k = tt * 32 + (l >> 4) * 8 + j;
        int nn = u * 16 + (l & 15);
        o[i] = f2h_bits(W[k * 160 + nn]);
    }
}

// level 1: partition packed (src<<8 | dst&255) into coarse-bucket-contiguous regions
__global__ __launch_bounds__(256) void part_kernel(const int* __restrict__ src,
                                                   const int* __restrict__ dst,
                                                   int* __restrict__ bucket_cursor,
                                                   unsigned int* __restrict__ pairs, int E) {
    __shared__ int bcnt[NBKT_MAX], bbase[NBKT_MAX], lc[NBKT_MAX];
    int tid = threadIdx.x;
    int per = (E + gridDim.x - 1) / gridDim.x;
    int beg = blockIdx.x * per;
    int end = min(beg + per, E);
    if (tid < NBKT_MAX) { bcnt[tid] = 0; lc[tid] = 0; }
    __syncthreads();
    for (int e = beg + tid; e < end; e += 256)
        atomicAdd(&bcnt[dst[e] >> BKT_SH], 1);
    __syncthreads();
    if (tid < NBKT_MAX)
        bbase[tid] = bcnt[tid] ? atomicAdd(&bucket_cursor[tid], bcnt[tid]) : 0;
    __syncthreads();
    for (int e = beg + tid; e < end; e += 256) {
        int d = dst[e];
        int b = d >> BKT_SH;
        int pos = bbase[b] + atomicAdd(&lc[b], 1);
        pairs[pos] = ((unsigned int)src[e] << BKT_SH) | (unsigned int)(d & (NBKT_MAX - 1));
    }
}

// level 2: per-bucket exact CSR build + local scatter + fused x*inv f16 pre-scale
__global__ __launch_bounds__(1024) void bucket_csr_kernel(const unsigned int* __restrict__ pairs,
                                                          const int* __restrict__ bucket_base,
                                                          int* __restrict__ row_off,
                                                          float* __restrict__ inv,
                                                          int* __restrict__ ssrc,
                                                          const float* __restrict__ x,
                                                          unsigned short* __restrict__ xs,
                                                          int n) {
    __shared__ int h[NBKT_MAX];
    __shared__ int ws[4];
    __shared__ float sinv[NBKT_MAX];
    int tid = threadIdx.x;
    int b = blockIdx.x;
    int node0 = b << BKT_SH;
    int beg = bucket_base[b], end = bucket_base[b + 1];
    if (tid < NBKT_MAX) h[tid] = 0;
    __syncthreads();
    for (int j = beg + tid; j < end; j += 1024)
        atomicAdd(&h[pairs[j] & (NBKT_MAX - 1)], 1);
    __syncthreads();
    int cntv = (tid < NBKT_MAX) ? h[tid] : 0;
    __syncthreads();
    int lane = tid & 63, wid = tid >> 6;
    int incl = cntv;
    #pragma unroll
    for (int off = 1; off < 64; off <<= 1) {
        int u = __shfl_up(incl, off);
        if (lane >= off) incl += u;
    }
    if (tid < NBKT_MAX && lane == 63) ws[wid] = incl;
    __syncthreads();
    if (tid == 0) {
        int r = 0;
        #pragma unroll
        for (int i = 0; i < 4; ++i) { int t = ws[i]; ws[i] = r; r += t; }
    }
    __syncthreads();
    int excl = (tid < NBKT_MAX) ? (ws[wid] + incl - cntv) : 0;
    if (tid < NBKT_MAX) {
        float iv = rsqrtf((float)(cntv + 1));    // +1 = self loop
        int node = node0 + tid;
        if (node < n) {
            row_off[node] = beg + excl;
            inv[node] = iv;
        }
        sinv[tid] = iv;
        h[tid] = excl;
    }
    if (tid == 0 && (node0 + NBKT_MAX) >= n) row_off[n] = end;
    __syncthreads();
    for (int j = beg + tid; j < end; j += 1024) {
        unsigned int p = pairs[j];
        int pos = beg + atomicAdd(&h[p & (NBKT_MAX - 1)], 1);
        ssrc[pos] = (int)(p >> BKT_SH);
    }
    // fused pre-scale: xs[node] = f16(x[node] * inv[node]) for this bucket's nodes
    for (int idx = tid; idx < NBKT_MAX * 32; idx += 1024) {
        int nd = node0 + (idx >> 5);
        if (nd < n) {
            float w = sinv[idx >> 5];
            float4 v = ((const float4*)x)[(size_t)nd * 32 + (idx & 31)];
            ushort4 o;
            o.x = f2h_bits(v.x * w); o.y = f2h_bits(v.y * w);
            o.z = f2h_bits(v.z * w); o.w = f2h_bits(v.w * w);
            ((ushort4*)xs)[(size_t)nd * 32 + (idx & 31)] = o;
        }
    }
}

// ---------------- fused layer v3: 4-wave agg -> LDS -> split MFMA GEMM -> coalesced epilogue ----------------
// v2 + LDS-staged output: the MFMA epilogue's scattered 2B stores doubled WRITE_SIZE
// (31.25 vs 16.3 MB, R11 counters) via partial-line RMW. v3 stages the 16x160 output
// tile in LDS (row-padded against bank aliasing), then streams it out as one
// contiguous block region with uint4/float4 stores. smem is reused between the
// phase-1 A-tile and the output tile (afr fragments are in registers by then).

template <int CIN, int OUTMODE>
__global__ __launch_bounds__(256) void fused_layer_kernel(const unsigned short* __restrict__ in_s,
                                                          const float* __restrict__ inv,
                                                          const int* __restrict__ row_off,
                                                          const int* __restrict__ ssrc,
                                                          const unsigned short* __restrict__ Bp,
                                                          const float* __restrict__ sc,
                                                          const float* __restrict__ sh,
                                                          float* __restrict__ CoutF,
                                                          unsigned short* __restrict__ CoutB,
                                                          int n) {
    constexpr int LPR = CIN / 8;          // lanes per row (uint4 = 8 ch)
    constexpr int G   = 64 / LPR;         // concurrent edges per wave
    constexpr int RB  = CIN * 2;          // row bytes
    constexpr int KT  = CIN / 32;         // MFMA K-tiles
    constexpr int STR = CIN + 8;          // phase-1 LDS row stride (ch)
    constexpr int OSTR = (OUTMODE == 0) ? 164 : 168;   // staging row stride (elems), padded
    constexpr int SM_A = 16 * STR * 2;
    constexpr int SM_O = (OUTMODE == 0) ? 16 * OSTR * 4 : 16 * OSTR * 2;
    constexpr int SMB  = SM_A > SM_O ? SM_A : SM_O;
    __shared__ __align__(16) char smem[SMB];

    int tid  = threadIdx.x;
    int wv   = tid >> 6;
    int lane = tid & 63;
    int node0 = blockIdx.x * 16;
    int g  = lane / LPR;
    int cl = lane - g * LPR;
    bool act = g < G;
    int lb = cl * 16;
    const char* bptr = (const char*)in_s;
    auto hrow = (unsigned short (*)[STR])smem;

    // ---- phase 1: each wave aggregates its 4 nodes into the shared LDS A-tile ----
    for (int i = 0; i < 4; ++i) {
        int row = wv * 4 + i;
        int node = node0 + row;
        if (node >= n) {
            if (lane < LPR) {
                uint4 z = {0u, 0u, 0u, 0u};
                *(uint4*)&hrow[row][cl * 8] = z;
            }
            continue;
        }
        int beg = row_off[node], end = row_off[node + 1];

        h2 acc[4];
        #pragma unroll
        for (int k = 0; k < 4; ++k) acc[k] = (h2){(_Float16)0.f, (_Float16)0.f};

        if (g == 0) {   // self-loop term
            uint4 r = *(const uint4*)(bptr + (size_t)node * RB + lb);
            addpk16(acc, r);
        }

        int e = act ? beg + g : end;
        for (; e + G < end; e += 2 * G) {
            int s0 = ssrc[e], s1 = ssrc[e + G];
            uint4 r0 = *(const uint4*)(bptr + (size_t)s0 * RB + lb);
            uint4 r1 = *(const uint4*)(bptr + (size_t)s1 * RB + lb);
            addpk16(acc, r0);
            addpk16(acc, r1);
        }
        if (e < end) {
            uint4 r = *(const uint4*)(bptr + (size_t)ssrc[e] * RB + lb);
            addpk16(acc, r);
        }

        // cross-group combine (packed f16)
        if (G == 4) {
            #pragma unroll
            for (int k = 0; k < 4; ++k) acc[k] += u2h(__shfl(h2u(acc[k]), lane + 32));
            #pragma unroll
            for (int k = 0; k < 4; ++k) acc[k] += u2h(__shfl(h2u(acc[k]), lane + 16));
        } else {
            #pragma unroll
            for (int k = 0; k < 4; ++k) {
                unsigned int ua = __shfl(h2u(acc[k]), lane + 20);
                unsigned int ub = __shfl(h2u(acc[k]), lane + 40);
                acc[k] += u2h(ua) + u2h(ub);
            }
        }

        if (lane < LPR) {
            float wi = inv[node];      // final deg-norm scale in fp32
            uint4 o;
            o.x = pkh((float)acc[0].x * wi, (float)acc[0].y * wi);
            o.y = pkh((float)acc[1].x * wi, (float)acc[1].y * wi);
            o.z = pkh((float)acc[2].x * wi, (float)acc[2].y * wi);
            o.w = pkh((float)acc[3].x * wi, (float)acc[3].y * wi);
            *(uint4*)&hrow[row][cl * 8] = o;
        }
    }
    __syncthreads();

    // ---- phase 2: load A-fragments to registers, then free smem for output staging ----
    int m = lane & 15, q = lane >> 4;
    const f16x8* Bf = (const f16x8*)Bp;    // frag idx = (t*10+u)*64 + lane

    f16x8 afr[KT];
    #pragma unroll
    for (int t = 0; t < KT; ++t) afr[t] = *(const f16x8*)&hrow[m][t * 32 + q * 8];
    __syncthreads();                       // all afr reads complete; smem reusable

    // column-tiles split across the 4 waves; stage outputs in LDS
    for (int u = wv; u < 10; u += 4) {
        facc4 acc = (facc4){0.f, 0.f, 0.f, 0.f};
        #pragma unroll
        for (int t = 0; t < KT; ++t) {
            f16x8 bf = Bf[(t * 10 + u) * 64 + lane];
            acc = __builtin_amdgcn_mfma_f32_16x16x32_f16(afr[t], bf, acc, 0, 0, 0);
        }
        // D layout: col = lane&15 (within tile), row = q*4 + reg
        int c = u * 16 + m;
        float scv = sc[c], shv = sh[c];
        if (OUTMODE == 1) {
            auto stg = (unsigned short (*)[OSTR])smem;
            #pragma unroll
            for (int r = 0; r < 4; ++r) {
                int row = q * 4 + r;
                int rr = node0 + row;
                if (rr < n) {
                    float v = fmaxf(acc[r] * scv + shv, 0.f);
                    stg[row][c] = f2h_bits(v * inv[rr]);
                }
            }
        } else {
            auto stg = (float (*)[OSTR])smem;
            #pragma unroll
            for (int r = 0; r < 4; ++r) {
                int row = q * 4 + r;
                float v = fmaxf(acc[r] * scv + shv, 0.f);
                stg[row][c] = v;
            }
        }
    }
    __syncthreads();

    // ---- phase 3: coalesced write-out of the block's contiguous output region ----
    if (OUTMODE == 1) {
        auto stg = (const unsigned short (*)[OSTR])smem;
        for (int idx = tid; idx < 16 * 20; idx += 256) {      // 20 uint4 per 160-ch row
            int row = idx / 20, off = idx - row * 20;
            int node = node0 + row;
            if (node < n)
                *(uint4*)(CoutB + (size_t)node * 160 + off * 8) = *(const uint4*)&stg[row][off * 8];
        }
    } else {
        auto stg = (const float (*)[OSTR])smem;
        for (int idx = tid; idx < 16 * 40; idx += 256) {      // 40 float4 per 160-ch row
            int row = idx / 40, off = idx - row * 40;
            int node = node0 + row;
            if (node < n)
                *(float4*)(CoutF + (size_t)node * 160 + off * 4) = *(const float4*)&stg[row][off * 4];
        }
    }
}

// ---------------- mean pool (sorted batch) + MLP head ----------------

__global__ __launch_bounds__(256) void pool_head_kernel(const float* __restrict__ h,
                                                        const int* __restrict__ batch,
                                                        const float* __restrict__ Wc1,
                                                        const float* __restrict__ bc1,
                                                        const float* __restrict__ Wc2,
                                                        const float* __restrict__ bc2,
                                                        float* __restrict__ out, int n) {
    __shared__ float4 part[6][40];
    __shared__ float pooled[160];
    __shared__ float z[80];
    __shared__ int range[2];
    int g = blockIdx.x;
    int t = threadIdx.x;
    if (t < 2) {
        int target = g + t;
        int lo = 0, hi = n;
        while (lo < hi) {
            int mid = (lo + hi) >> 1;
            if (batch[mid] < target) lo = mid + 1; else hi = mid;
        }
        range[t] = lo;
    }
    __syncthreads();
    int lo = range[0], hi = range[1];
    int sub = t / 40, c4 = t - sub * 40;
    if (sub < 6) {
        float4 a = {0.f, 0.f, 0.f, 0.f};
        for (int r = lo + sub; r < hi; r += 6) {
            float4 v = ((const float4*)(h + (size_t)r * 160))[c4];
            a.x += v.x; a.y += v.y; a.z += v.z; a.w += v.w;
        }
        part[sub][c4] = a;
    }
    __syncthreads();
    if (t < 40) {
        float4 s = {0.f, 0.f, 0.f, 0.f};
        #pragma unroll
        for (int i = 0; i < 6; ++i) {
            float4 p = part[i][t];
            s.x += p.x; s.y += p.y; s.z += p.z; s.w += p.w;
        }
        float ic = 1.f / fmaxf((float)(hi - lo), 1.f);
        pooled[t * 4 + 0] = s.x * ic;
        pooled[t * 4 + 1] = s.y * ic;
        pooled[t * 4 + 2] = s.z * ic;
        pooled[t * 4 + 3] = s.w * ic;
    }
    __syncthreads();
    if (t < 80) {
        float s = bc1[t];
        for (int k = 0; k < 160; ++k) s += pooled[k] * Wc1[k * 80 + t];
        z[t] = fmaxf(s, 0.f);
    }
    __syncthreads();
    if (t < 2) {
        float s = bc2[t];
        for (int k = 0; k < 80; ++k) s += z[k] * Wc2[k * 2 + t];
        out[g * 2 + t] = s;
    }
}

// ---------------- launch ----------------

static inline size_t align256(size_t x) { return (x + 255) & ~(size_t)255; }

extern "C" void kernel_launch(void* const* d_in, const int* in_sizes, int n_in,
                              void* d_out, int out_size, void* d_ws, size_t ws_size,
                              hipStream_t stream) {
    const float* x   = (const float*)d_in[0];
    const int* ei    = (const int*)d_in[1];
    const int* batch = (const int*)d_in[2];
    const float* W1  = (const float*)d_in[3];
    const float* b1  = (const float*)d_in[4];
    const float* W2  = (const float*)d_in[5];
    const float* b2  = (const float*)d_in[6];
    const float* W3  = (const float*)d_in[7];
    const float* b3  = (const float*)d_in[8];
    const float* g1  = (const float*)d_in[9];
    const float* be1 = (const float*)d_in[10];
    const float* m1  = (const float*)d_in[11];
    const float* v1  = (const float*)d_in[12];
    const float* g2  = (const float*)d_in[13];
    const float* be2 = (const float*)d_in[14];
    const float* m2  = (const float*)d_in[15];
    const float* v2  = (const float*)d_in[16];
    const float* g3  = (const float*)d_in[17];
    const float* be3 = (const float*)d_in[18];
    const float* m3  = (const float*)d_in[19];
    const float* v3  = (const float*)d_in[20];
    const float* Wc1 = (const float*)d_in[21];
    const float* bc1 = (const float*)d_in[22];
    const float* Wc2 = (const float*)d_in[23];
    const float* bc2 = (const float*)d_in[24];
    float* out = (float*)d_out;

    const int N = in_sizes[2];          // 50000
    const int E = in_sizes[1] / 2;      // 1600000
    const int* src = ei;
    const int* dst = ei + E;

    char* w = (char*)d_ws;
    int*   row_off = (int*)w;             w += align256((size_t)(N + 1) * 4);
    float* inv     = (float*)w;           w += align256((size_t)N * 4);
    int*   ssrc    = (int*)w;             w += align256((size_t)E * 4);
    unsigned int* pairs = (unsigned int*)w; w += align256((size_t)E * 4);
    int*   cg      = (int*)w;             w += align256((size_t)HIST_BLOCKS * NBKT_MAX * 4);
    int*   bucket_base   = (int*)w;       w += align256((size_t)(NBKT_MAX + 1) * 4);
    int*   bucket_cursor = (int*)w;       w += align256((size_t)NBKT_MAX * 4);
    float* scsh    = (float*)w;           w += align256((size_t)6 * HDIM * 4);
    unsigned short* W1p = (unsigned short*)w;  w += align256((size_t)FDIM_IN * HDIM * 2);
    unsigned short* W2p = (unsigned short*)w;  w += align256((size_t)HDIM * HDIM * 2);
    unsigned short* W3p = (unsigned short*)w;  w += align256((size_t)HDIM * HDIM * 2);
    unsigned short* xs_bf  = (unsigned short*)w;  w += align256((size_t)N * FDIM_IN * 2);
    unsigned short* h1_bf  = (unsigned short*)w;  w += align256((size_t)N * HDIM * 2);
    unsigned short* h2_bf  = (unsigned short*)w;  w += align256((size_t)N * HDIM * 2);
    float* bufC    = (float*)w;           w += align256((size_t)N * HDIM * 4);
    float* sc1 = scsh, *sh1 = scsh + 160, *sc2 = scsh + 320, *sh2 = scsh + 480,
         * sc3 = scsh + 640, *sh3 = scsh + 800;

    // two-level counting sort by dst -> row_off, ssrc, inv (+ fused x pre-scale)
    coarse_hist_kernel<<<HIST_BLOCKS, 256, 0, stream>>>(dst, cg, E);

    PrepArgs pa0 = {b1, g1, be1, m1, v1, sc1, sh1};
    PrepArgs pa1 = {b2, g2, be2, m2, v2, sc2, sh2};
    PrepArgs pa2 = {b3, g3, be3, m3, v3, sc3, sh3};
    int packTotal = 128 * 160 + 2 * 160 * 160;
    int setupBlocks = 4 + (packTotal + 255) / 256;
    setup_kernel<<<setupBlocks, 256, 0, stream>>>(cg, bucket_base, bucket_cursor,
                                                  pa0, pa1, pa2, W1, W2, W3, W1p, W2p, W3p);

    part_kernel<<<256, 256, 0, stream>>>(src, dst, bucket_cursor, pairs, E);
    int nbkt = (N + NBKT_MAX - 1) >> BKT_SH;
    bucket_csr_kernel<<<nbkt, 1024, 0, stream>>>(pairs, bucket_base, row_off, inv, ssrc, x, xs_bf, N);

    int gF = (N + 15) / 16;

    // fused agg+GEMM per layer (ping-pong buffers, no aliasing)
    fused_layer_kernel<128, 1><<<gF, 256, 0, stream>>>(xs_bf, inv, row_off, ssrc, W1p, sc1, sh1, nullptr, h1_bf, N);
    fused_layer_kernel<160, 1><<<gF, 256, 0, stream>>>(h1_bf, inv, row_off, ssrc, W2p, sc2, sh2, nullptr, h2_bf, N);
    fused_layer_kernel<160, 0><<<gF, 256, 0, stream>>>(h2_bf, inv, row_off, ssrc, W3p, sc3, sh3, bufC, nullptr, N);

    pool_head_kernel<<<N_GRAPHS, 256, 0, stream>>>(bufC, batch, Wc1, bc1, Wc2, bc2, out, N);
}